// Round 1
// baseline (155.487 us; speedup 1.0000x reference)
//
#include <hip/hip_runtime.h>
#include <stdint.h>

// Problem constants (from reference)
#define NB   4      // batch
#define CC   256    // channels (K)
#define WR   60     // cells per row/col
#define MM   3600   // HR*WR (M and N of the GEMM)
#define HH   480
#define WW   480
#define GS   8

typedef __bf16 bf16x8 __attribute__((ext_vector_type(8)));
typedef float  f32x4  __attribute__((ext_vector_type(4)));

// round-to-nearest-even fp32 -> bf16 (data has no NaN/inf)
__device__ __forceinline__ unsigned short f2bf(float x) {
  union { float f; unsigned u; } v; v.f = x;
  unsigned r = v.u + 0x7fffu + ((v.u >> 16) & 1u);
  return (unsigned short)(r >> 16);
}

// async global->LDS, 16B per lane; LDS dest is wave-uniform base + lane*16
__device__ __forceinline__ void gload_lds16(const void* g, void* l) {
  __builtin_amdgcn_global_load_lds(
      (const __attribute__((address_space(1))) void*)g,
      (__attribute__((address_space(3))) void*)l, 16, 0, 0);
}

// ---------------------------------------------------------------------------
// Kernel 1: transpose+cast  desc[b][c][m] (f32) -> dst[b][m][c] (bf16)
// 64x64 tiles via LDS, coalesced read (along m) and write (along c).
// ---------------------------------------------------------------------------
__global__ void transpose_cast(const float* __restrict__ src,
                               unsigned short* __restrict__ dst) {
  __shared__ float tile[64][65];
  int b  = blockIdx.z;
  int c0 = blockIdx.y * 64;
  int m0 = blockIdx.x * 64;
  int tx = threadIdx.x & 63, ty = threadIdx.x >> 6;
  const float* s = src + (size_t)b * CC * MM;
  int m = m0 + tx;
  if (m < MM) {
#pragma unroll
    for (int i = 0; i < 16; ++i) {
      int cl = i * 4 + ty;
      tile[cl][tx] = s[(size_t)(c0 + cl) * MM + m];
    }
  }
  __syncthreads();
  unsigned short* d = dst + (size_t)b * MM * CC;
#pragma unroll
  for (int i = 0; i < 16; ++i) {
    int ml = i * 4 + ty;
    if (m0 + ml < MM)
      d[(size_t)(m0 + ml) * CC + c0 + tx] = f2bf(tile[tx][ml]);
  }
}

// ---------------------------------------------------------------------------
// Kernel 2: per warped cell: w_grid (homography warp of cell centers),
// vm (product over 8x8 vis block), and vm_sum (wave-reduced atomic).
// ---------------------------------------------------------------------------
__global__ void prep_grid(const float* __restrict__ homo,
                          const float* __restrict__ vis,
                          float2* __restrict__ wg,
                          float* __restrict__ vmarr,
                          float* __restrict__ vm_sum) {
  int idx = blockIdx.x * 256 + threadIdx.x;
  float p = 0.f;
  if (idx < NB * MM) {
    int b = idx / MM, cell = idx - b * MM;
    int h1 = cell / WR, w1 = cell - h1 * WR;
    float gx = (float)(w1 * GS + GS / 2);
    float gy = (float)(h1 * GS + GS / 2);
    const float* Hm = homo + b * 9;
    float X = Hm[0] * gx + Hm[1] * gy + Hm[2];
    float Y = Hm[3] * gx + Hm[4] * gy + Hm[5];
    float Z = Hm[6] * gx + Hm[7] * gy + Hm[8];
    wg[idx] = make_float2(X / Z, Y / Z);
    const float* v = vis + (size_t)b * HH * WW + (size_t)(h1 * GS) * WW + w1 * GS;
    float prod = 1.f;
#pragma unroll
    for (int rr = 0; rr < GS; ++rr) {
      const float4* rp = (const float4*)(v + (size_t)rr * WW);
      float4 a = rp[0], c = rp[1];
      prod *= a.x * a.y * a.z * a.w;
      prod *= c.x * c.y * c.z * c.w;
    }
    vmarr[idx] = prod;
    p = prod;
  }
#pragma unroll
  for (int off = 32; off; off >>= 1) p += __shfl_down(p, off, 64);
  if ((threadIdx.x & 63) == 0) atomicAdd(vm_sum, p);
}

// ---------------------------------------------------------------------------
// Kernel 3: fused bf16 MFMA GEMM + hinge loss partial reduction.
// Block: 128x128 C-tile, 256 threads = 4 waves (2x2), each wave 64x64 via
// 4x4 grid of 16x16x32 bf16 MFMAs. A[m][k], B^T[n][k] both row-major bf16.
// ---------------------------------------------------------------------------
__global__ __launch_bounds__(256, 2) void hinge_gemm(
    const unsigned short* __restrict__ Ab, const unsigned short* __restrict__ Bb,
    const float2* __restrict__ wg, const float* __restrict__ vmarr,
    float* __restrict__ loss_sum) {
  __shared__ unsigned short As[128 * 32];   // [m][k], 8 KB
  __shared__ unsigned short Bs[128 * 32];   // [n][k], 8 KB
  __shared__ float partial[4];

  int b  = blockIdx.z;
  int m0 = blockIdx.y * 128, n0 = blockIdx.x * 128;
  int tid  = threadIdx.x;
  int lane = tid & 63, w = tid >> 6;
  int quad = lane >> 4, r = lane & 15;
  int wave_m = w >> 1, wave_n = w & 1;

  const unsigned short* Abase = Ab + (size_t)b * MM * CC;
  const unsigned short* Bbase = Bb + (size_t)b * MM * CC;

  f32x4 acc[4][4];
#pragma unroll
  for (int i = 0; i < 4; ++i)
#pragma unroll
    for (int j = 0; j < 4; ++j)
#pragma unroll
      for (int k = 0; k < 4; ++k) acc[i][j][k] = 0.f;

  // staging: 8KB/tile = 512 x 16B chunks; 256 threads -> 2 passes.
  // chunk = pass*256 + tid; LDS offset = chunk*16 == (row*32 + qc*8) elems.
  int row0 = tid >> 2,        qc0 = tid & 3;
  int row1 = (256 + tid) >> 2, qc1 = tid & 3;   // (256+tid)&3 == tid&3
  int am0 = min(m0 + row0, MM - 1), am1 = min(m0 + row1, MM - 1);
  int bn0 = min(n0 + row0, MM - 1), bn1 = min(n0 + row1, MM - 1);
  char* ldsA0 = (char*)As + (size_t)(w * 64) * 16;
  char* ldsA1 = (char*)As + (size_t)(256 + w * 64) * 16;
  char* ldsB0 = (char*)Bs + (size_t)(w * 64) * 16;
  char* ldsB1 = (char*)Bs + (size_t)(256 + w * 64) * 16;

  for (int kt = 0; kt < 8; ++kt) {
    int k0 = kt * 32;
    gload_lds16(Abase + (size_t)am0 * CC + k0 + qc0 * 8, ldsA0);
    gload_lds16(Abase + (size_t)am1 * CC + k0 + qc1 * 8, ldsA1);
    gload_lds16(Bbase + (size_t)bn0 * CC + k0 + qc0 * 8, ldsB0);
    gload_lds16(Bbase + (size_t)bn1 * CC + k0 + qc1 * 8, ldsB1);
    __syncthreads();

    bf16x8 af[4], bfr[4];
#pragma unroll
    for (int t = 0; t < 4; ++t) {
      af[t]  = *(const bf16x8*)(As + (wave_m * 64 + t * 16 + r) * 32 + quad * 8);
      bfr[t] = *(const bf16x8*)(Bs + (wave_n * 64 + t * 16 + r) * 32 + quad * 8);
    }
#pragma unroll
    for (int mt = 0; mt < 4; ++mt)
#pragma unroll
      for (int nt = 0; nt < 4; ++nt)
        acc[mt][nt] = __builtin_amdgcn_mfma_f32_16x16x32_bf16(
            af[mt], bfr[nt], acc[mt][nt], 0, 0, 0);
    __syncthreads();
  }

  // Epilogue: C/D layout col = lane&15 (n), row = quad*4 + reg (m).
  float sum = 0.f;
  const float2* wgb = wg + (size_t)b * MM;
  const float*  vmb = vmarr + (size_t)b * MM;
#pragma unroll
  for (int nt = 0; nt < 4; ++nt) {
    int gn = n0 + wave_n * 64 + nt * 16 + r;
    bool nok = gn < MM;
    float2 wgv = nok ? wgb[gn] : make_float2(1e9f, 1e9f);
    float  vmv = nok ? vmb[gn] : 0.f;
#pragma unroll
    for (int mt = 0; mt < 4; ++mt) {
      int gmb = m0 + wave_m * 64 + mt * 16 + quad * 4;
#pragma unroll
      for (int reg = 0; reg < 4; ++reg) {
        int gm = gmb + reg;
        if (nok && gm < MM) {
          int h1 = gm / WR, w1 = gm - h1 * WR;
          float gx = (float)(w1 * GS + GS / 2);
          float gy = (float)(h1 * GS + GS / 2);
          float dx = gx - wgv.x, dy = gy - wgv.y;
          float d2 = dx * dx + dy * dy;
          float dot = acc[mt][nt][reg];
          float val = (d2 <= 56.25f) ? fmaxf(1.0f - dot, 0.f)
                                     : fmaxf(dot - 0.2f, 0.f);
          sum += vmv * val;
        }
      }
    }
  }
#pragma unroll
  for (int off = 32; off; off >>= 1) sum += __shfl_down(sum, off, 64);
  if (lane == 0) partial[w] = sum;
  __syncthreads();
  if (tid == 0)
    atomicAdd(loss_sum, partial[0] + partial[1] + partial[2] + partial[3]);
}

// ---------------------------------------------------------------------------
// Kernel 4: out = loss_sum / (hr*wr * vm_sum) * LOSS_LAMBDA
// ---------------------------------------------------------------------------
__global__ void finalize_k(const float* __restrict__ sums, float* __restrict__ out) {
  out[0] = sums[0] / ((float)MM * sums[1]);
}

extern "C" void kernel_launch(void* const* d_in, const int* in_sizes, int n_in,
                              void* d_out, int out_size, void* d_ws, size_t ws_size,
                              hipStream_t stream) {
  const float* desc1 = (const float*)d_in[0];
  const float* desc2 = (const float*)d_in[1];
  const float* homo  = (const float*)d_in[2];
  const float* vis   = (const float*)d_in[3];
  float* out = (float*)d_out;

  char* ws = (char*)d_ws;
  // workspace layout (total ~14.92 MB)
  unsigned short* Ab = (unsigned short*)ws;                    // 7,372,800 B
  unsigned short* Bb = (unsigned short*)(ws + 7372800);        // 7,372,800 B
  float2* wg   = (float2*)(ws + 14745600);                     //   115,200 B
  float*  vm   = (float*) (ws + 14860800);                     //    57,600 B
  float*  sums = (float*) (ws + 14918400);                     // [0]=loss, [1]=vm_sum

  hipMemsetAsync(sums, 0, 2 * sizeof(float), stream);

  dim3 tgrid(57, 4, NB);  // ceil(3600/64), 256/64, batch
  transpose_cast<<<tgrid, 256, 0, stream>>>(desc1, Ab);
  transpose_cast<<<tgrid, 256, 0, stream>>>(desc2, Bb);

  prep_grid<<<(NB * MM + 255) / 256, 256, 0, stream>>>(homo, vis, wg, vm, sums + 1);

  dim3 ggrid(29, 29, NB);  // ceil(3600/128)^2 x batch
  hinge_gemm<<<ggrid, 256, 0, stream>>>(Ab, Bb, wg, vm, sums);

  finalize_k<<<1, 1, 0, stream>>>(sums, out);
}

// Round 2
// 146.956 us; speedup vs baseline: 1.0581x; 1.0581x over previous
//
#include <hip/hip_runtime.h>
#include <stdint.h>

// Problem constants (from reference)
#define NB   4      // batch
#define CC   256    // channels (K)
#define WR   60     // cells per row/col
#define MM   3600   // HR*WR (M and N of the GEMM)
#define HH   480
#define WW   480
#define GS   8
#define MT   29     // ceil(3600/128) tiles per side

typedef __bf16 bf16x8 __attribute__((ext_vector_type(8)));
typedef float  f32x4  __attribute__((ext_vector_type(4)));

// round-to-nearest-even fp32 -> bf16 (data has no NaN/inf)
__device__ __forceinline__ unsigned short f2bf(float x) {
  union { float f; unsigned u; } v; v.f = x;
  unsigned r = v.u + 0x7fffu + ((v.u >> 16) & 1u);
  return (unsigned short)(r >> 16);
}

// async global->LDS, 16B per lane; LDS dest is wave-uniform base + lane*16
__device__ __forceinline__ void gload_lds16(const void* g, void* l) {
  __builtin_amdgcn_global_load_lds(
      (const __attribute__((address_space(1))) void*)g,
      (__attribute__((address_space(3))) void*)l, 16, 0, 0);
}

// ---------------------------------------------------------------------------
// Kernel 1: pack desc[b][c][m] (f32) into MFMA-fragment-ordered bf16 tiles:
//   packed[b][mtile][kt][ ((h*4 + t)*64 + lane)*8 + e ]
// where m = mtile*128 + h*64 + t*16 + (lane&15), k = kt*32 + (lane>>4)*8 + e.
// This makes BOTH the GEMM's global_load_lds staging and its ds_read_b128
// fragment reads fully lane-linear (conflict-free, no address math).
// Tail rows (m >= 3600) are written as zeros so the GEMM needs no m-guard.
// One launch handles both descriptors (blockIdx.z selects).
// ---------------------------------------------------------------------------
__global__ __launch_bounds__(256) void pack_frag(
    const float* __restrict__ d1, const float* __restrict__ d2,
    unsigned short* __restrict__ p1, unsigned short* __restrict__ p2) {
  __shared__ float tile[32][132];   // [k_local][m_local], 132*4=528B rows (16B-aligned)
  int kt = blockIdx.x, mtile = blockIdx.y, z = blockIdx.z;
  int b = z & 3;
  const float* src = ((z >> 2) ? d2 : d1) + (size_t)b * CC * MM + (size_t)(kt * 32) * MM;
  unsigned short* dst = ((z >> 2) ? p2 : p1) + ((size_t)(b * MT + mtile) * 8 + kt) * 4096;
  int tid = threadIdx.x;

  // coalesced read: 32 k-rows x 128 m (float4 along m)
#pragma unroll
  for (int pass = 0; pass < 4; ++pass) {
    int cid = pass * 256 + tid;          // [0,1024)
    int c = cid >> 5, m4 = (cid & 31) * 4;
    int gm = mtile * 128 + m4;
    float4 v;
    if (gm + 3 < MM) {
      v = *(const float4*)(src + (size_t)c * MM + gm);
    } else {
      v.x = (gm     < MM) ? src[(size_t)c * MM + gm]     : 0.f;
      v.y = (gm + 1 < MM) ? src[(size_t)c * MM + gm + 1] : 0.f;
      v.z = (gm + 2 < MM) ? src[(size_t)c * MM + gm + 2] : 0.f;
      v.w = (gm + 3 < MM) ? src[(size_t)c * MM + gm + 3] : 0.f;
    }
    *(float4*)&tile[c][m4] = v;
  }
  __syncthreads();

  // fragment-order write: 512 slots of 16B; slot s = ((h*4+t)*64 + lane)
#pragma unroll
  for (int pass = 0; pass < 2; ++pass) {
    int s = pass * 256 + tid;            // [0,512)
    int lane = s & 63, tt = (s >> 6) & 3, h = s >> 8;
    int m_local = h * 64 + tt * 16 + (lane & 15);
    int k_local = (lane >> 4) * 8;
    unsigned short o[8];
    if (mtile * 128 + m_local < MM) {
#pragma unroll
      for (int e = 0; e < 8; ++e) o[e] = f2bf(tile[k_local + e][m_local]);
    } else {
#pragma unroll
      for (int e = 0; e < 8; ++e) o[e] = 0;
    }
    ((uint4*)dst)[s] = *(const uint4*)o;
  }
}

// ---------------------------------------------------------------------------
// Kernel 2: per warped cell: w_grid (homography warp of cell centers),
// vm (product over 8x8 vis block), and vm_sum (wave-reduced atomic).
// ---------------------------------------------------------------------------
__global__ void prep_grid(const float* __restrict__ homo,
                          const float* __restrict__ vis,
                          float2* __restrict__ wg,
                          float* __restrict__ vmarr,
                          float* __restrict__ vm_sum) {
  int idx = blockIdx.x * 256 + threadIdx.x;
  float p = 0.f;
  if (idx < NB * MM) {
    int b = idx / MM, cell = idx - b * MM;
    int h1 = cell / WR, w1 = cell - h1 * WR;
    float gx = (float)(w1 * GS + GS / 2);
    float gy = (float)(h1 * GS + GS / 2);
    const float* Hm = homo + b * 9;
    float X = Hm[0] * gx + Hm[1] * gy + Hm[2];
    float Y = Hm[3] * gx + Hm[4] * gy + Hm[5];
    float Z = Hm[6] * gx + Hm[7] * gy + Hm[8];
    wg[idx] = make_float2(X / Z, Y / Z);
    const float* v = vis + (size_t)b * HH * WW + (size_t)(h1 * GS) * WW + w1 * GS;
    float prod = 1.f;
#pragma unroll
    for (int rr = 0; rr < GS; ++rr) {
      const float4* rp = (const float4*)(v + (size_t)rr * WW);
      float4 a = rp[0], c = rp[1];
      prod *= a.x * a.y * a.z * a.w;
      prod *= c.x * c.y * c.z * c.w;
    }
    vmarr[idx] = prod;
    p = prod;
  }
#pragma unroll
  for (int off = 32; off; off >>= 1) p += __shfl_down(p, off, 64);
  if ((threadIdx.x & 63) == 0) atomicAdd(vm_sum, p);
}

// ---------------------------------------------------------------------------
// Kernel 3: fused bf16 MFMA GEMM + hinge loss partial reduction.
// Inputs are fragment-order packed tiles: staging is contiguous 8KB blocks,
// fragment ds_read_b128 is lane-linear (conflict-free).
// Block: 128x128 C-tile, 4 waves (2x2), each 64x64 via 4x4 16x16x32 MFMAs.
// ---------------------------------------------------------------------------
__global__ __launch_bounds__(256, 4) void hinge_gemm(
    const unsigned short* __restrict__ Ap, const unsigned short* __restrict__ Bp,
    const float2* __restrict__ wg, const float* __restrict__ vmarr,
    float* __restrict__ loss_sum) {
  __shared__ unsigned short As[4096];   // one kt-tile, 8 KB
  __shared__ unsigned short Bs[4096];
  __shared__ float partial[4];

  int b = blockIdx.z;
  int mtile = blockIdx.y, ntile = blockIdx.x;
  int tid = threadIdx.x, lane = tid & 63, w = tid >> 6;
  int quad = lane >> 4, r = lane & 15;
  int wave_m = w >> 1, wave_n = w & 1;

  const char* Abase = (const char*)(Ap + ((size_t)(b * MT + mtile) * 8) * 4096);
  const char* Bbase = (const char*)(Bp + ((size_t)(b * MT + ntile) * 8) * 4096);

  f32x4 acc[4][4];
#pragma unroll
  for (int i = 0; i < 4; ++i)
#pragma unroll
    for (int j = 0; j < 4; ++j)
#pragma unroll
      for (int k = 0; k < 4; ++k) acc[i][j][k] = 0.f;

  char* ldsA = (char*)As + w * 1024;   // wave-uniform; +lane*16 implicit
  char* ldsB = (char*)Bs + w * 1024;
  const char* pa = (const char*)As + wave_m * 4096 + lane * 16;
  const char* pb = (const char*)Bs + wave_n * 4096 + lane * 16;

  for (int kt = 0; kt < 8; ++kt) {
    const char* ga = Abase + kt * 8192;
    const char* gb = Bbase + kt * 8192;
    gload_lds16(ga + tid * 16, ldsA);
    gload_lds16(ga + 4096 + tid * 16, ldsA + 4096);
    gload_lds16(gb + tid * 16, ldsB);
    gload_lds16(gb + 4096 + tid * 16, ldsB + 4096);
    __syncthreads();

    bf16x8 af[4], bfr[4];
#pragma unroll
    for (int t = 0; t < 4; ++t) {
      af[t]  = *(const bf16x8*)(pa + t * 1024);
      bfr[t] = *(const bf16x8*)(pb + t * 1024);
    }
#pragma unroll
    for (int mt = 0; mt < 4; ++mt)
#pragma unroll
      for (int nt = 0; nt < 4; ++nt)
        acc[mt][nt] = __builtin_amdgcn_mfma_f32_16x16x32_bf16(
            af[mt], bfr[nt], acc[mt][nt], 0, 0, 0);
    __syncthreads();
  }

  // Epilogue. C/D layout: col(n) = lane&15, row(m) = quad*4 + reg.
  // Tail m-rows are zero-padded in Ap -> dot=0 -> hinge=0; no m-guard needed.
  float gxv[16], gyv[16];
#pragma unroll
  for (int mt = 0; mt < 4; ++mt)
#pragma unroll
    for (int reg = 0; reg < 4; ++reg) {
      int gm = mtile * 128 + wave_m * 64 + mt * 16 + quad * 4 + reg;
      float gmf = (float)gm;
      // h1 = gm/60 via floor((2*gm+1)/120): 1/120 margin >> fp rounding error
      float h1 = floorf(fmaf(gmf, (1.0f / 60.0f), (1.0f / 120.0f)));
      float w1 = fmaf(h1, -60.f, gmf);
      gxv[mt * 4 + reg] = fmaf(w1, 8.f, 4.f);
      gyv[mt * 4 + reg] = fmaf(h1, 8.f, 4.f);
    }

  float sum = 0.f;
  const float2* wgb = wg + (size_t)b * MM;
  const float*  vmb = vmarr + (size_t)b * MM;
#pragma unroll
  for (int nt = 0; nt < 4; ++nt) {
    int gn = ntile * 128 + wave_n * 64 + nt * 16 + r;
    bool nok = gn < MM;
    float2 wgv = nok ? wgb[gn] : make_float2(1e9f, 1e9f);
    float  vmv = nok ? vmb[gn] : 0.f;
#pragma unroll
    for (int mt = 0; mt < 4; ++mt)
#pragma unroll
      for (int reg = 0; reg < 4; ++reg) {
        float dot = acc[mt][nt][reg];
        float dx = gxv[mt * 4 + reg] - wgv.x;
        float dy = gyv[mt * 4 + reg] - wgv.y;
        float d2 = fmaf(dx, dx, dy * dy);
        float a = (d2 <= 56.25f) ? (1.0f - dot) : (dot - 0.2f);
        sum = fmaf(vmv, fmaxf(a, 0.f), sum);
      }
  }
#pragma unroll
  for (int off = 32; off; off >>= 1) sum += __shfl_down(sum, off, 64);
  if (lane == 0) partial[w] = sum;
  __syncthreads();
  if (tid == 0)
    atomicAdd(loss_sum, partial[0] + partial[1] + partial[2] + partial[3]);
}

// ---------------------------------------------------------------------------
// Kernel 4: out = loss_sum / (hr*wr * vm_sum) * LOSS_LAMBDA
// ---------------------------------------------------------------------------
__global__ void finalize_k(const float* __restrict__ sums, float* __restrict__ out) {
  out[0] = sums[0] / ((float)MM * sums[1]);
}

extern "C" void kernel_launch(void* const* d_in, const int* in_sizes, int n_in,
                              void* d_out, int out_size, void* d_ws, size_t ws_size,
                              hipStream_t stream) {
  const float* desc1 = (const float*)d_in[0];
  const float* desc2 = (const float*)d_in[1];
  const float* homo  = (const float*)d_in[2];
  const float* vis   = (const float*)d_in[3];
  float* out = (float*)d_out;

  char* ws = (char*)d_ws;
  // packed size per desc: 4 * 29 * 8 * 4096 elems * 2B = 7,602,176 B
  unsigned short* Ap = (unsigned short*)ws;
  unsigned short* Bp = (unsigned short*)(ws + 7602176);
  float2* wg   = (float2*)(ws + 15204352);                 // 115,200 B
  float*  vm   = (float*) (ws + 15319552);                 //  57,600 B
  float*  sums = (float*) (ws + 15377152);                 // [0]=loss, [1]=vm_sum

  hipMemsetAsync(sums, 0, 2 * sizeof(float), stream);

  dim3 pgrid(8, MT, 2 * NB);   // kt x mtile x (desc,b)
  pack_frag<<<pgrid, 256, 0, stream>>>(desc1, desc2, Ap, Bp);

  prep_grid<<<(NB * MM + 255) / 256, 256, 0, stream>>>(homo, vis, wg, vm, sums + 1);

  dim3 ggrid(MT, MT, NB);
  hinge_gemm<<<ggrid, 256, 0, stream>>>(Ap, Bp, wg, vm, sums);

  finalize_k<<<1, 1, 0, stream>>>(sums, out);
}